// Round 6
// baseline (1560.298 us; speedup 1.0000x reference)
//
#include <hip/hip_runtime.h>
#include <math.h>

#define NBLK 64

typedef __attribute__((ext_vector_type(8))) short short8;
typedef __attribute__((ext_vector_type(8))) _Float16 f16x8;
typedef __attribute__((ext_vector_type(4))) float f32x4;

__device__ __forceinline__ void split_f16(float f, unsigned short& h, unsigned short& l){
  _Float16 hh = (_Float16)f;
  _Float16 ll = (_Float16)(f - (float)hh);
  h = __builtin_bit_cast(unsigned short, hh);
  l = __builtin_bit_cast(unsigned short, ll);
}

__global__ __launch_bounds__(256, 1) void lstm_persist(
    const float* __restrict__ x,
    const float* __restrict__ hidden0,
    const float* __restrict__ W_hid,
    const float* __restrict__ b_hid,
    const float* __restrict__ W_ih,
    const float* __restrict__ W_hh,
    const float* __restrict__ b_ih,
    const float* __restrict__ b_hh,
    float* __restrict__ out,
    float* __restrict__ out_h0,
    unsigned* __restrict__ flags,     // [64] one-time x-init barrier
    unsigned* __restrict__ hsteps,    // [256][32][512] packed (f16hi<<16|f16lo); 0xFFFFFFFF = not ready
    unsigned short* __restrict__ xhi, // [32][256][64] f16 bits
    unsigned short* __restrict__ xlo)
{
  __shared__ float gs[2][32][33];     // double-buffered gate exchange

  const int tid  = threadIdx.x;
  const int bid  = blockIdx.x;
  const int lane = tid & 63;
  const int wid  = tid >> 6;   // 0..3
  const int r    = wid >> 1;   // 0 = i/f quadrants, 1 = g/o
  const int cc   = wid & 1;    // batch half
  const int m    = lane & 15;
  const int g    = lane >> 4;
  const int J0   = bid * 8;    // block owns hidden cols J0..J0+7
  const int gid  = bid * 256 + tid;
  const int cb   = tid >> 3;   // owner thread -> (batch cb, col J0+cj)
  const int cj   = tid & 7;

  // ---------------- init: h0 = hidden0 @ W_hid^T + b_hid ----------------
  {
    int b = gid >> 9, hc = gid & 511;
    const float* hv = hidden0 + b * 64;
    const float* wv = W_hid + hc * 64;
    float acc = b_hid[hc];
    #pragma unroll
    for (int d = 0; d < 64; d += 4){
      float4 a = *(const float4*)(hv + d);
      float4 w = *(const float4*)(wv + d);
      acc += a.x*w.x + a.y*w.y + a.z*w.z + a.w*w.w;
    }
    out_h0[gid] = acc;                       // second output
    unsigned short hh, ll; split_f16(acc, hh, ll);
    unsigned packed = ((unsigned)hh << 16) | (unsigned)ll;  // finite => hi16 != 0xFFFF
    asm volatile("global_store_dword %0, %1, off sc0 sc1" :: "v"(hsteps + gid), "v"(packed) : "memory");
  }
  // ---------------- init: x -> f16 hi/lo (write-through) ----------------
  {
    const float4* x4 = (const float4*)x;
    #pragma unroll
    for (int k = 0; k < 8; ++k){
      int v = gid + k * 16384;
      float4 f = x4[v];
      unsigned short ha,la,hb2,lb2,hc2,lc2,hd,ld;
      split_f16(f.x,ha,la); split_f16(f.y,hb2,lb2);
      split_f16(f.z,hc2,lc2); split_f16(f.w,hd,ld);
      uint2 ph, pl;
      ph.x = (unsigned)ha | ((unsigned)hb2 << 16);
      ph.y = (unsigned)hc2 | ((unsigned)hd << 16);
      pl.x = (unsigned)la | ((unsigned)lb2 << 16);
      pl.y = (unsigned)lc2 | ((unsigned)ld << 16);
      asm volatile("global_store_dwordx2 %0, %1, off sc0 sc1" :: "v"(xhi + (size_t)v*4), "v"(ph) : "memory");
      asm volatile("global_store_dwordx2 %0, %1, off sc0 sc1" :: "v"(xlo + (size_t)v*4), "v"(pl) : "memory");
    }
  }
  // ---------------- own c0, exact f32 ----------------
  float c_state;
  {
    const float* hv = hidden0 + cb * 64;
    const float* wv = W_hid + (J0 + cj) * 64;
    float acc = b_hid[J0 + cj];
    #pragma unroll
    for (int d = 0; d < 64; d += 4){
      float4 a = *(const float4*)(hv + d);
      float4 w = *(const float4*)(wv + d);
      acc += a.x*w.x + a.y*w.y + a.z*w.z + a.w*w.w;
    }
    c_state = acc;
  }

  // gate row for this lane's A-fragment (quadrant-major)
  const int R = (r == 0) ? ((m < 8) ? (J0 + m) : (512 + J0 + m - 8))
                         : ((m < 8) ? (1024 + J0 + m) : (1536 + J0 + (m - 8)));

  // ---------------- W_hh fragments -> registers (once) ----------------
  f16x8 whh_hi[16], whh_lo[16];
  #pragma unroll
  for (int kc = 0; kc < 16; ++kc){
    const float* p = W_hh + R * 512 + kc * 32 + g * 8;
    float4 f0 = *(const float4*)p;
    float4 f1 = *(const float4*)(p + 4);
    float fs[8] = {f0.x,f0.y,f0.z,f0.w,f1.x,f1.y,f1.z,f1.w};
    short8 hb, lb;
    #pragma unroll
    for (int i = 0; i < 8; ++i){
      unsigned short hh, ll; split_f16(fs[i], hh, ll);
      hb[i] = (short)hh; lb[i] = (short)ll;
    }
    whh_hi[kc] = __builtin_bit_cast(f16x8, hb);
    whh_lo[kc] = __builtin_bit_cast(f16x8, lb);
  }

  const float bias_i = b_ih[J0+cj]      + b_hh[J0+cj];
  const float bias_f = b_ih[512+J0+cj]  + b_hh[512+J0+cj];
  const float bias_g = b_ih[1024+J0+cj] + b_hh[1024+J0+cj];
  const float bias_o = b_ih[1536+J0+cj] + b_hh[1536+J0+cj];

  // ---------------- one-time barrier: x f16 conversion complete ----------------
  asm volatile("s_waitcnt vmcnt(0)" ::: "memory");
  __syncthreads();
  if (tid == 0){
    unsigned one = 1;
    asm volatile("global_store_dword %0, %1, off sc0 sc1" :: "v"(flags + bid), "v"(one) : "memory");
  }
  {
    const unsigned* fp = flags + lane;
    while (true){
      unsigned fv;
      asm volatile("global_load_dword %0, %1, off sc0 sc1\n\ts_waitcnt vmcnt(0)"
                   : "=v"(fv) : "v"(fp) : "memory");
      if (__all((int)(fv >= 1u))) break;
      __builtin_amdgcn_s_sleep(1);
    }
  }

  // persistent x@W_ih prefix-sum accumulators
  const int xb = cc * 16 + m;          // this lane's batch row for B-frags
  f32x4 axc0 = {0.f,0.f,0.f,0.f}, axc1 = axc0, axc2 = axc0;

  auto xpart = [&](int t){
    #pragma unroll
    for (int kc = 0; kc < 2; ++kc){
      const float* p = W_ih + (size_t)R * 16384 + (size_t)t * 64 + kc * 32 + g * 8;
      float4 f0 = *(const float4*)p;
      float4 f1 = *(const float4*)(p + 4);
      float fs[8] = {f0.x,f0.y,f0.z,f0.w,f1.x,f1.y,f1.z,f1.w};
      short8 hb, lb;
      #pragma unroll
      for (int i = 0; i < 8; ++i){
        unsigned short hh, ll; split_f16(fs[i], hh, ll);
        hb[i] = (short)hh; lb[i] = (short)ll;
      }
      f16x8 ahi = __builtin_bit_cast(f16x8, hb);
      f16x8 alo = __builtin_bit_cast(f16x8, lb);
      size_t off = ((size_t)xb * 256 + (size_t)t) * 64 + kc * 32 + g * 8;
      f16x8 bhi = __builtin_bit_cast(f16x8, *(const short8*)(xhi + off));
      f16x8 blo = __builtin_bit_cast(f16x8, *(const short8*)(xlo + off));
      axc0 = __builtin_amdgcn_mfma_f32_16x16x32_f16(ahi, bhi, axc0, 0,0,0);
      axc1 = __builtin_amdgcn_mfma_f32_16x16x32_f16(ahi, blo, axc1, 0,0,0);
      axc2 = __builtin_amdgcn_mfma_f32_16x16x32_f16(alo, bhi, axc2, 0,0,0);
    }
  };
  xpart(0);

  // depth-2 pipelined per-fragment poll + MFMA.
  // Chunk kc = 32B = 8 packed dwords at hb + kc*32 + g*8.
  #define ISSUE2(PTR, DA, DB) \
    asm volatile("global_load_dwordx4 %0, %1, off sc0 sc1" : "=v"(DA) : "v"(PTR)); \
    asm volatile("global_load_dwordx4 %0, %1, off sc0 sc1" : "=v"(DB) : "v"((PTR)+4));

  #define PROCK(KC, DA, DB, WAITS, DOISS) { \
    asm volatile("s_waitcnt vmcnt(" WAITS ")" ::: "memory"); \
    __builtin_amdgcn_sched_barrier(0); \
    while (true){ \
      int bad = (DA.x==0xFFFFFFFFu)||(DA.y==0xFFFFFFFFu)||(DA.z==0xFFFFFFFFu)||(DA.w==0xFFFFFFFFu)|| \
                (DB.x==0xFFFFFFFFu)||(DB.y==0xFFFFFFFFu)||(DB.z==0xFFFFFFFFu)||(DB.w==0xFFFFFFFFu); \
      if (!__any(bad)) break; \
      const unsigned* rp = hb + (KC)*32 + g*8; \
      ISSUE2(rp, DA, DB) \
      asm volatile("s_waitcnt vmcnt(0)" ::: "memory"); \
      __builtin_amdgcn_sched_barrier(0); \
    } \
    uint4 cA = DA, cB = DB; \
    if (DOISS){ const unsigned* np = hb + ((KC)+2)*32 + g*8; ISSUE2(np, DA, DB) } \
    uint4 hiv, lov; \
    hiv.x = __builtin_amdgcn_perm(cA.y, cA.x, 0x07060302u); \
    hiv.y = __builtin_amdgcn_perm(cA.w, cA.z, 0x07060302u); \
    hiv.z = __builtin_amdgcn_perm(cB.y, cB.x, 0x07060302u); \
    hiv.w = __builtin_amdgcn_perm(cB.w, cB.z, 0x07060302u); \
    lov.x = __builtin_amdgcn_perm(cA.y, cA.x, 0x05040100u); \
    lov.y = __builtin_amdgcn_perm(cA.w, cA.z, 0x05040100u); \
    lov.z = __builtin_amdgcn_perm(cB.y, cB.x, 0x05040100u); \
    lov.w = __builtin_amdgcn_perm(cB.w, cB.z, 0x05040100u); \
    f16x8 bhi = __builtin_bit_cast(f16x8, hiv); \
    f16x8 blo = __builtin_bit_cast(f16x8, lov); \
    acc0 = __builtin_amdgcn_mfma_f32_16x16x32_f16(whh_hi[KC], bhi, acc0, 0,0,0); \
    acc1 = __builtin_amdgcn_mfma_f32_16x16x32_f16(whh_hi[KC], blo, acc1, 0,0,0); \
    acc2 = __builtin_amdgcn_mfma_f32_16x16x32_f16(whh_lo[KC], bhi, acc2, 0,0,0); \
  }

  for (int t = 0; t < 256; ++t){
    const unsigned* hb = hsteps + (size_t)t * 16384 + (size_t)xb * 512;

    uint4 d0a, d0b, d1a, d1b;
    { const unsigned* p0 = hb + g*8;      ISSUE2(p0, d0a, d0b) }
    { const unsigned* p1 = hb + 32 + g*8; ISSUE2(p1, d1a, d1b) }

    f32x4 acc0 = {0.f,0.f,0.f,0.f}, acc1 = acc0, acc2 = acc0;

    PROCK( 0, d0a, d0b, "2", 1)
    PROCK( 1, d1a, d1b, "2", 1)
    PROCK( 2, d0a, d0b, "2", 1)
    PROCK( 3, d1a, d1b, "2", 1)
    PROCK( 4, d0a, d0b, "2", 1)
    PROCK( 5, d1a, d1b, "2", 1)
    PROCK( 6, d0a, d0b, "2", 1)
    PROCK( 7, d1a, d1b, "2", 1)
    PROCK( 8, d0a, d0b, "2", 1)
    PROCK( 9, d1a, d1b, "2", 1)
    PROCK(10, d0a, d0b, "2", 1)
    PROCK(11, d1a, d1b, "2", 1)
    PROCK(12, d0a, d0b, "2", 1)
    PROCK(13, d1a, d1b, "2", 1)
    PROCK(14, d0a, d0b, "2", 0)
    PROCK(15, d1a, d1b, "0", 0)

    // ---- gate pre-activations -> LDS (double-buffered, ONE sync per step) ----
    f32x4 tot = acc0 + acc1 + acc2 + axc0 + axc1 + axc2;
    #pragma unroll
    for (int q = 0; q < 4; ++q)
      gs[t & 1][r * 16 + g * 4 + q][cc * 16 + m] = tot[q];
    __syncthreads();

    // ---- gates + state update; h(t+1) store is fire-and-forget ----
    {
      float pi = gs[t & 1][cj][cb]      + bias_i;
      float pf = gs[t & 1][8 + cj][cb]  + bias_f;
      float pg = gs[t & 1][16 + cj][cb] + bias_g;
      float po = gs[t & 1][24 + cj][cb] + bias_o;
      float ig = 1.f / (1.f + expf(-pi));
      float fg = 1.f / (1.f + expf(-pf));
      float gg = tanhf(pg);
      float og = 1.f / (1.f + expf(-po));
      c_state = fg * c_state + ig * gg;
      float hval = og * tanhf(c_state);
      if (t < 255){
        unsigned short hh, ll; split_f16(hval, hh, ll);
        unsigned packed = ((unsigned)hh << 16) | (unsigned)ll;   // hi16 never 0xFFFF (finite)
        asm volatile("global_store_dword %0, %1, off sc0 sc1"
                     :: "v"(hsteps + (size_t)(t+1)*16384 + (size_t)cb*512 + J0 + cj), "v"(packed) : "memory");
      }
      out[(size_t)(cb * 256 + t) * 512 + J0 + cj] = fmaxf(hval, 0.f);
    }

    if (t < 255) xpart(t + 1);   // W_ih stream + cumsum MFMA overlaps h-visibility window
  }
  #undef PROCK
  #undef ISSUE2
}

// ---------------------------------------------------------------------------
extern "C" void kernel_launch(void* const* d_in, const int* in_sizes, int n_in,
                              void* d_out, int out_size, void* d_ws, size_t ws_size,
                              hipStream_t stream) {
  const float* x       = (const float*)d_in[0];
  const float* hidden0 = (const float*)d_in[1];
  const float* W_hid   = (const float*)d_in[2];
  const float* b_hid   = (const float*)d_in[3];
  const float* W_ih    = (const float*)d_in[4];
  const float* W_hh    = (const float*)d_in[5];
  const float* b_ih    = (const float*)d_in[6];
  const float* b_hh    = (const float*)d_in[7];

  float* out    = (float*)d_out;
  float* out_h0 = out + (size_t)32 * 256 * 512;

  char* ws = (char*)d_ws;
  unsigned*       flags  = (unsigned*)ws;                          // 256 B
  unsigned short* xhi    = (unsigned short*)(ws + 4096);           // 1 MB
  unsigned short* xlo    = (unsigned short*)(ws + 4096 + (1<<20)); // 1 MB
  unsigned*       hsteps = (unsigned*)(ws + 4096 + (2<<20));       // 16 MB: [256][32][512] dwords

  (void)hipMemsetAsync(flags, 0, 256, stream);
  (void)hipMemsetAsync(hsteps, 0xFF, (size_t)256 * 16384 * 4, stream);  // sentinel

  lstm_persist<<<NBLK, 256, 0, stream>>>(
      x, hidden0, W_hid, b_hid, W_ih, W_hh, b_ih, b_hh,
      out, out_h0, flags, hsteps, xhi, xlo);
}